// Round 9
// baseline (415.298 us; speedup 1.0000x reference)
//
#include <hip/hip_runtime.h>
#include <stdint.h>

// TimeVaryingDelayLine forward — LDS multi-pass gather, v7.
//
// R8 lesson: 512-thread blocks are hard-capped at 128 VGPRs by the compiler
// (spills regardless of __launch_bounds__). Only proven spill-free shell is
// R4's: 256 threads, __launch_bounds__(256,2), 32 elems/thread (96-reg state,
// VGPR_Count=96). v7 = that shell + the two good v5 ideas:
//  - Branchless membership scan (sub + clamp + ALWAYS-issued ds_read2 + lerp
//    + cndmask-add): no exec-mask divergence, so the compiler batch-issues
//    independent ds_read2s and ILP hides LDS latency (R4/R5's hidden cost).
//    Non-member lanes clamp to one slot -> broadcast, no extra conflicts.
//  - Overlap-by-4 pass windows: stride 8188 floats = 32752B (16B multiple):
//    staging stays 16B-aligned, never straddles the series buffer end, and a
//    tap pair never straddles a window -> zero edge cases.
//  - Double buffer 2x32KB (64KB LDS -> 2 blocks/CU like R4), stage-ahead via
//    global_load_lds(16B), one barrier per pass, NPASS=6.

#define MAX_DELAY 40000
#define T_LEN     1000000
#define XPAD      (MAX_DELAY + T_LEN)   // 1,040,000 floats per series
#define CHUNK     8192                  // output elems per block
#define S_ELEMS   8192                  // floats per stage buffer
#define S_BYTES   32768
#define STRIDE_E  (S_ELEMS - 4)         // 8188 floats between pass windows
#define STRIDE_B  (STRIDE_E * 4)        // 32752 bytes
#define VALID_MAX (STRIDE_B - 4)        // membership: ub <= 32748
#define NPASS     6                     // covers b1 max 192760 <= 5*32752+32748
#define CPS       123                   // ceil(T_LEN/CHUNK)
#define NXCD      8

typedef __attribute__((address_space(3))) uint32_t       lds_u32;
typedef const __attribute__((address_space(1))) uint32_t glb_u32;

__global__ __launch_bounds__(256, 2) void tvdl_kernel(
    const float* __restrict__ x,
    const float* __restrict__ dt,
    const float* __restrict__ buf,
    float* __restrict__ y,
    int chunk_per_xcd)
{
    __shared__ float lds[2][S_ELEMS];

    int bid = blockIdx.x;
    int lb  = (bid & (NXCD - 1)) * chunk_per_xcd + (bid >> 3);  // XCD-contiguous
    int nc  = lb / CPS;                 // series 0..15
    int c   = lb - nc * CPS;            // chunk 0..122
    int t0  = c * CHUNK;
    int tid = threadIdx.x;

    const float* __restrict__ xs  = x   + (size_t)nc * T_LEN;
    const float* __restrict__ bs  = buf + (size_t)nc * MAX_DELAY;
    const float* __restrict__ dts = dt  + (size_t)nc * T_LEN;
    float*       __restrict__ ys  = y   + (size_t)nc * T_LEN;

    // ---- per-element setup: read dt once, keep (b1, frac, acc) in regs ----
    int   b1[8][4];     // byte offset of tap1 relative to window start t0
    float fr[8][4];
    float acc[8][4];

#pragma unroll
    for (int k = 0; k < 8; ++k) {
        int go   = (k * 256 + tid) * 4;
        int lidx = t0 + go;
        int lc   = lidx > T_LEN - 4 ? T_LEN - 4 : lidx;   // tail-chunk clamp
        float4 d4 = *reinterpret_cast<const float4*>(dts + lc);
        float dv[4] = {d4.x, d4.y, d4.z, d4.w};
#pragma unroll
        for (int j = 0; j < 4; ++j) {
            float dvj = dv[j];
            int   i0  = (int)dvj;                 // dt >= 0 -> trunc == floor
            fr[k][j]  = dvj - (float)i0;
            b1[k][j]  = (MAX_DELAY - 1 + (go + j) - i0) * 4;
            acc[k][j] = 0.0f;
        }
    }

    // ---- staging: pass p window = xpad floats [t0 + p*STRIDE_E, +8192) ----
    // 8 x (64 lanes x 16B) per wave, 32KB/block; 16B-aligned sources; never
    // straddles the series buffer end (g mult of 4, boundary mult of 4).
#define STAGE(b, p)                                                          \
    {                                                                        \
        _Pragma("unroll")                                                    \
        for (int q = 0; q < 8; ++q) {                                        \
            int g = t0 + (p) * STRIDE_E + (q * 256 + tid) * 4;               \
            if (g > XPAD - 4) g = XPAD - 4;   /* tail clamp, mult-of-4 */    \
            const float* src = (g >= MAX_DELAY) ? (xs + (g - MAX_DELAY))     \
                                                : (bs + g);                  \
            float* dst = lds[b] + (size_t)(q * 256 + (tid & 192)) * 4;       \
            __builtin_amdgcn_global_load_lds((glb_u32*)src, (lds_u32*)dst,   \
                                             16, 0, 0);                      \
        }                                                                    \
    }

    STAGE(0, 0);
    __syncthreads();                    // vmcnt(0) drain -> lds[0] ready

#pragma unroll
    for (int p = 0; p < NPASS; ++p) {
        const int cur = p & 1;
        if (p + 1 < NPASS) STAGE(cur ^ 1, p + 1);   // async, lands by barrier

        const char* lb0 = (const char*)lds[cur];
#pragma unroll
        for (int k = 0; k < 8; ++k) {
#pragma unroll
            for (int j = 0; j < 4; ++j) {
                unsigned ub = (unsigned)(b1[k][j] - p * STRIDE_B);
                unsigned ad = ub < (unsigned)VALID_MAX ? ub : (unsigned)VALID_MAX;
                const float* lp = (const float*)(lb0 + ad);   // ds_read2_b32
                float t1v = lp[0];
                float t0v = lp[1];
                float r   = fmaf(fr[k][j], t1v - t0v, t0v);   // lerp
                acc[k][j] += (ub <= (unsigned)VALID_MAX) ? r : 0.0f;
            }
        }

        if (p + 1 < NPASS) __syncthreads();   // reads done + next stage landed
    }
#undef STAGE

    // ---- store ----
#pragma unroll
    for (int k = 0; k < 8; ++k) {
        int go = (k * 256 + tid) * 4;
        if (t0 + go < T_LEN) {
            *reinterpret_cast<float4*>(ys + t0 + go) =
                make_float4(acc[k][0], acc[k][1], acc[k][2], acc[k][3]);
        }
    }
}

extern "C" void kernel_launch(void* const* d_in, const int* in_sizes, int n_in,
                              void* d_out, int out_size, void* d_ws, size_t ws_size,
                              hipStream_t stream) {
    const float* x   = (const float*)d_in[0];
    const float* dt  = (const float*)d_in[1];
    const float* buf = (const float*)d_in[2];
    float* y = (float*)d_out;

    int nseries = out_size / T_LEN;                 // 16
    int blocks  = nseries * CPS;                    // 1968 = 8 * 246
    int chunk_per_xcd = blocks / NXCD;              // 246
    tvdl_kernel<<<blocks, 256, 0, stream>>>(x, dt, buf, y, chunk_per_xcd);
}

// Round 10
// 74.246 us; speedup vs baseline: 5.5935x; 5.5935x over previous
//
#include <hip/hip_runtime.h>
#include <stdint.h>

// TimeVaryingDelayLine forward — LDS multi-pass gather, v8.
//
// R9 lesson: branchless always-issued ds_read2 batches 32 reads -> ~100 live
// regs on top of 96-reg state -> spill bomb. Branchy scan (R4/R5) is proven
// spill-free at 92-96 VGPR. R5-vs-R4 arithmetic showed dbuf DID overlap, but
// NPASS=6 doubled scan VALU and halved compute-per-barrier. v8 combines:
//  - R5 shell: 256 threads, branchy scan, double buffer, stage-ahead,
//    one barrier per pass (proven spill-free).
//  - NPASS=3 via 2x64KB buffers (128KB LDS, 1 block/CU, 4 waves).
//  - Overlap-by-4 pass windows (stride 16380 floats = 65520B): staging stays
//    16B-aligned and never straddles the series buffer end (R6 bug excluded),
//    and a tap pair never straddles a window -> single membership test per
//    pass (no 3-way edge cluster).
//
// Block = 256 threads x 32 elems = 8192 contiguous t of one series.

#define MAX_DELAY 40000
#define T_LEN     1000000
#define XPAD      (MAX_DELAY + T_LEN)   // 1,040,000 floats per series
#define CHUNK     8192                  // output elems per block
#define S_ELEMS   16384                 // floats per stage buffer
#define S_BYTES   65536
#define STRIDE_E  (S_ELEMS - 4)         // 16380 floats between pass windows
#define STRIDE_B  (STRIDE_E * 4)        // 65520 bytes
#define VALID_MAX (STRIDE_B - 4)        // membership: ub <= 65516 (mult of 4)
#define NPASS     3                     // max b1 = 192760 <= 2*65520+65516
#define CPS       123                   // ceil(T_LEN/CHUNK)
#define NXCD      8

typedef __attribute__((address_space(3))) uint32_t       lds_u32;
typedef const __attribute__((address_space(1))) uint32_t glb_u32;

__global__ __launch_bounds__(256, 1) void tvdl_kernel(
    const float* __restrict__ x,
    const float* __restrict__ dt,
    const float* __restrict__ buf,
    float* __restrict__ y,
    int chunk_per_xcd)
{
    __shared__ float lds[2][S_ELEMS];

    int bid = blockIdx.x;
    int lb  = (bid & (NXCD - 1)) * chunk_per_xcd + (bid >> 3);  // XCD-contiguous
    int nc  = lb / CPS;                 // series 0..15
    int c   = lb - nc * CPS;            // chunk 0..122
    int t0  = c * CHUNK;
    int tid = threadIdx.x;

    const float* __restrict__ xs  = x   + (size_t)nc * T_LEN;
    const float* __restrict__ bs  = buf + (size_t)nc * MAX_DELAY;
    const float* __restrict__ dts = dt  + (size_t)nc * T_LEN;
    float*       __restrict__ ys  = y   + (size_t)nc * T_LEN;

    // ---- per-element setup: read dt once, keep (b1, frac, acc) in regs ----
    int   b1[8][4];     // byte offset of tap1 relative to window start t0
    float fr[8][4];
    float acc[8][4];

#pragma unroll
    for (int k = 0; k < 8; ++k) {
        int go   = (k * 256 + tid) * 4;
        int lidx = t0 + go;
        int lc   = lidx > T_LEN - 4 ? T_LEN - 4 : lidx;   // tail-chunk clamp
        float4 d4 = *reinterpret_cast<const float4*>(dts + lc);
        float dv[4] = {d4.x, d4.y, d4.z, d4.w};
#pragma unroll
        for (int j = 0; j < 4; ++j) {
            float dvj = dv[j];
            int   i0  = (int)dvj;                 // dt >= 0 -> trunc == floor
            fr[k][j]  = dvj - (float)i0;
            b1[k][j]  = (MAX_DELAY - 1 + (go + j) - i0) * 4;
            acc[k][j] = 0.0f;
        }
    }

    // ---- staging: pass p window = xpad floats [t0 + p*STRIDE_E, +16384) ----
    // 16 x (64 lanes x 16B) per wave = 64KB/block; sources 16B-aligned
    // (g mult of 4); buffer-region loads cap at bs[39996..39999].
#define STAGE(b, p)                                                          \
    {                                                                        \
        _Pragma("unroll")                                                    \
        for (int q = 0; q < 16; ++q) {                                       \
            int g = t0 + (p) * STRIDE_E + (q * 256 + tid) * 4;               \
            if (g > XPAD - 4) g = XPAD - 4;   /* tail clamp, mult-of-4 */    \
            const float* src = (g >= MAX_DELAY) ? (xs + (g - MAX_DELAY))     \
                                                : (bs + g);                  \
            float* dst = lds[b] + (size_t)(q * 256 + (tid & 192)) * 4;       \
            __builtin_amdgcn_global_load_lds((glb_u32*)src, (lds_u32*)dst,   \
                                             16, 0, 0);                      \
        }                                                                    \
    }

    STAGE(0, 0);
    __syncthreads();                    // vmcnt(0) drain -> lds[0] ready

#pragma unroll
    for (int p = 0; p < NPASS; ++p) {
        const int cur = p & 1;
        if (p + 1 < NPASS) STAGE(cur ^ 1, p + 1);   // async; lands by barrier

        const char* lb0 = (const char*)lds[cur];
#pragma unroll
        for (int k = 0; k < 8; ++k) {
#pragma unroll
            for (int j = 0; j < 4; ++j) {
                unsigned ub = (unsigned)(b1[k][j] - p * STRIDE_B);
                if (ub <= (unsigned)VALID_MAX) {      // single test, no edges
                    const float* lp = (const float*)(lb0 + ub);  // ds_read2
                    float t1v = lp[0];
                    float t0v = lp[1];
                    float f   = fr[k][j];
                    acc[k][j] = fmaf(1.0f - f, t0v, fmaf(f, t1v, acc[k][j]));
                }
            }
        }

        if (p + 1 < NPASS) __syncthreads();   // reads done + next stage landed
    }
#undef STAGE

    // ---- store ----
#pragma unroll
    for (int k = 0; k < 8; ++k) {
        int go = (k * 256 + tid) * 4;
        if (t0 + go < T_LEN) {
            *reinterpret_cast<float4*>(ys + t0 + go) =
                make_float4(acc[k][0], acc[k][1], acc[k][2], acc[k][3]);
        }
    }
}

extern "C" void kernel_launch(void* const* d_in, const int* in_sizes, int n_in,
                              void* d_out, int out_size, void* d_ws, size_t ws_size,
                              hipStream_t stream) {
    const float* x   = (const float*)d_in[0];
    const float* dt  = (const float*)d_in[1];
    const float* buf = (const float*)d_in[2];
    float* y = (float*)d_out;

    int nseries = out_size / T_LEN;                 // 16
    int blocks  = nseries * CPS;                    // 1968 = 8 * 246
    int chunk_per_xcd = blocks / NXCD;              // 246
    tvdl_kernel<<<blocks, 256, 0, stream>>>(x, dt, buf, y, chunk_per_xcd);
}